// Round 1
// baseline (2880.414 us; speedup 1.0000x reference)
//
#include <hip/hip_runtime.h>

#define N_NODES 165888
#define N_EDGES 3317760
#define HID 64
#define N_LAYERS 4
#define LN_EPS 1e-5f

__device__ __forceinline__ float wave_sum64(float v) {
    #pragma unroll
    for (int off = 32; off >= 1; off >>= 1)
        v += __shfl_xor(v, off, 64);
    return v;
}

// ---------------- CSR build ----------------

__global__ void k_hist(const int* __restrict__ dst, int* __restrict__ cnt) {
    int stride = gridDim.x * blockDim.x;
    for (int e = blockIdx.x * blockDim.x + threadIdx.x; e < N_EDGES; e += stride)
        atomicAdd(&cnt[dst[e]], 1);
}

__global__ void k_scan_block(const int* __restrict__ cnt, int* __restrict__ roff,
                             int* __restrict__ blksum) {
    __shared__ int s[256];
    int t = threadIdx.x;
    int i = blockIdx.x * 256 + t;
    int own = cnt[i];
    s[t] = own;
    __syncthreads();
    for (int off = 1; off < 256; off <<= 1) {
        int v = (t >= off) ? s[t - off] : 0;
        __syncthreads();
        s[t] += v;
        __syncthreads();
    }
    roff[i] = s[t] - own;            // exclusive within block
    if (t == 255) blksum[blockIdx.x] = s[255];
}

__global__ void k_scan_tops(const int* __restrict__ blksum, int* __restrict__ blkoff,
                            int* __restrict__ roff) {
    int run = 0;
    for (int b = 0; b < N_NODES / 256; ++b) { blkoff[b] = run; run += blksum[b]; }
    roff[N_NODES] = run;             // == N_EDGES
}

__global__ void k_scan_add(int* __restrict__ roff, const int* __restrict__ blkoff) {
    int stride = gridDim.x * blockDim.x;
    for (int i = blockIdx.x * blockDim.x + threadIdx.x; i < N_NODES; i += stride)
        roff[i] += blkoff[i >> 8];
}

__global__ void k_fill(const int* __restrict__ src, const int* __restrict__ dst,
                       const int* __restrict__ roff, int* __restrict__ cur,
                       int* __restrict__ csr) {
    int stride = gridDim.x * blockDim.x;
    for (int e = blockIdx.x * blockDim.x + threadIdx.x; e < N_EDGES; e += stride) {
        int d = dst[e];
        int p = atomicAdd(&cur[d], 1);
        csr[roff[d] + p] = src[e];
    }
}

// ---------------- input projection + residual ----------------

__global__ __launch_bounds__(256) void k_proj(
        const float* __restrict__ x,
        const float* __restrict__ Win, const float* __restrict__ bin,
        const float* __restrict__ Wres, const float* __restrict__ bres,
        float* __restrict__ h0, float* __restrict__ res) {
    __shared__ float wtres[64 * 64];   // wtres[k*64+j] = Wres[j][k]
    __shared__ float sh[4][64];
    for (int idx = threadIdx.x; idx < 4096; idx += 256) {
        int j = idx >> 6, k = idx & 63;
        wtres[k * 64 + j] = Wres[idx];
    }
    __syncthreads();
    int lane = threadIdx.x & 63;
    int w = threadIdx.x >> 6;
    const int G = N_NODES / 4;         // 4 nodes per block-iter (one per wave)
    float bi = bin[lane], br = bres[lane];
    for (int g = blockIdx.x; g < G; g += gridDim.x) {
        int n = g * 4 + w;
        float h = bi;
        #pragma unroll
        for (int k = 0; k < 9; ++k)
            h += x[n * 9 + k] * Win[lane * 9 + k];
        h0[(size_t)n * 64 + lane] = h;
        sh[w][lane] = h;
        __syncthreads();
        float r = br;
        #pragma unroll 8
        for (int k = 0; k < 64; ++k)
            r += wtres[k * 64 + lane] * sh[w][k];
        res[(size_t)n * 64 + lane] = r;
        __syncthreads();
    }
}

// ---------------- fused GraphConv layer ----------------
// h_new[n][j] = LN( sum_k Wroot[j][k]*h[n][k] + sum_k Wrel[j][k]*agg[n][k] + bc[j] )
//              -> leaky_relu -> + residual ;  agg[n] = sum_{e: dst=n} h[src_e]

__global__ __launch_bounds__(256) void k_layer(
        const float* __restrict__ hprev, float* __restrict__ hnext,
        const float* __restrict__ res,
        const int* __restrict__ roff, const int* __restrict__ csr,
        const float* __restrict__ Wroot, const float* __restrict__ Wrel,
        const float* __restrict__ bconv,
        const float* __restrict__ lng, const float* __restrict__ lnb) {
    __shared__ float wtr[64 * 64];     // wtr[k*64+j] = Wroot[j][k]
    __shared__ float wtl[64 * 64];     // wtl[k*64+j] = Wrel[j][k]
    __shared__ float shh[4][4][64];    // [wave][m][k] own row
    __shared__ float sha[4][4][64];    // [wave][m][k] aggregated row
    for (int idx = threadIdx.x; idx < 4096; idx += 256) {
        int j = idx >> 6, k = idx & 63;
        wtr[k * 64 + j] = Wroot[idx];
        wtl[k * 64 + j] = Wrel[idx];
    }
    __syncthreads();
    int lane = threadIdx.x & 63;
    int w = threadIdx.x >> 6;
    float bc = bconv[lane], g_ = lng[lane], b_ = lnb[lane];
    const int G = N_NODES / 16;        // 16 nodes per block-iter (4 per wave)
    for (int g = blockIdx.x; g < G; g += gridDim.x) {
        int nb = g * 16 + w * 4;
        #pragma unroll
        for (int m = 0; m < 4; ++m) {
            int n = nb + m;
            float agg = 0.f;
            int e0 = roff[n], e1 = roff[n + 1];
            for (int e = e0; e < e1; ++e) {
                int s = csr[e];
                agg += hprev[(size_t)s * 64 + lane];
            }
            sha[w][m][lane] = agg;
            shh[w][m][lane] = hprev[(size_t)n * 64 + lane];
        }
        __syncthreads();
        float acc0 = bc, acc1 = bc, acc2 = bc, acc3 = bc;
        #pragma unroll 8
        for (int k = 0; k < 64; ++k) {
            float wr = wtr[k * 64 + lane];
            float wl = wtl[k * 64 + lane];
            acc0 += wr * shh[w][0][k] + wl * sha[w][0][k];
            acc1 += wr * shh[w][1][k] + wl * sha[w][1][k];
            acc2 += wr * shh[w][2][k] + wl * sha[w][2][k];
            acc3 += wr * shh[w][3][k] + wl * sha[w][3][k];
        }
        float accs[4] = {acc0, acc1, acc2, acc3};
        #pragma unroll
        for (int m = 0; m < 4; ++m) {
            float v = accs[m];
            float mu = wave_sum64(v) * (1.f / 64.f);
            float d = v - mu;
            float var = wave_sum64(d * d) * (1.f / 64.f);
            float y = d * rsqrtf(var + LN_EPS) * g_ + b_;
            y = (y > 0.f) ? y : 0.01f * y;
            y += res[(size_t)(nb + m) * 64 + lane];
            hnext[(size_t)(nb + m) * 64 + lane] = y;
        }
        __syncthreads();
    }
}

// ---------------- output projection ----------------

__global__ void k_out(const float* __restrict__ h, const float* __restrict__ Wout,
                      const float* __restrict__ bout, float* __restrict__ out) {
    int stride = gridDim.x * blockDim.x;
    for (int idx = blockIdx.x * blockDim.x + threadIdx.x; idx < N_NODES * 9; idx += stride) {
        int n = idx / 9, c = idx - n * 9;
        const float* hr = h + (size_t)n * 64;
        const float* wr = Wout + c * 64;
        float acc = bout[c];
        #pragma unroll 16
        for (int k = 0; k < 64; ++k) acc += hr[k] * wr[k];
        out[idx] = acc;
    }
}

extern "C" void kernel_launch(void* const* d_in, const int* in_sizes, int n_in,
                              void* d_out, int out_size, void* d_ws, size_t ws_size,
                              hipStream_t stream) {
    const float* x     = (const float*)d_in[0];
    const int*   ei    = (const int*)d_in[1];     // [2, E] int32
    const float* Win   = (const float*)d_in[2];
    const float* bin   = (const float*)d_in[3];
    const float* Wrel  = (const float*)d_in[4];   // [4,64,64]
    const float* Wroot = (const float*)d_in[5];   // [4,64,64]
    const float* bconv = (const float*)d_in[6];   // [4,64]
    const float* Wres  = (const float*)d_in[7];
    const float* bres  = (const float*)d_in[8];
    const float* lng   = (const float*)d_in[9];
    const float* lnb   = (const float*)d_in[10];
    const float* Wout  = (const float*)d_in[11];
    const float* bout  = (const float*)d_in[12];
    float* out = (float*)d_out;

    char* p = (char*)d_ws;
    auto alloc = [&](size_t bytes) {
        char* r = p;
        p += (bytes + 255) & ~(size_t)255;
        return r;
    };
    float* h0   = (float*)alloc((size_t)N_NODES * 64 * 4);
    float* h1   = (float*)alloc((size_t)N_NODES * 64 * 4);
    float* res  = (float*)alloc((size_t)N_NODES * 64 * 4);
    int* csr    = (int*)alloc((size_t)N_EDGES * 4);
    int* cnt    = (int*)alloc((size_t)N_NODES * 4);
    int* cur    = (int*)alloc((size_t)N_NODES * 4);
    int* roff   = (int*)alloc((size_t)(N_NODES + 1) * 4);
    int* blk    = (int*)alloc(1024 * 4);
    int* blkoff = (int*)alloc(1024 * 4);

    const int* srcv = ei;
    const int* dstv = ei + N_EDGES;

    hipMemsetAsync(cnt, 0, (size_t)N_NODES * 4, stream);
    hipMemsetAsync(cur, 0, (size_t)N_NODES * 4, stream);
    k_hist<<<2048, 256, 0, stream>>>(dstv, cnt);
    k_scan_block<<<N_NODES / 256, 256, 0, stream>>>(cnt, roff, blk);
    k_scan_tops<<<1, 1, 0, stream>>>(blk, blkoff, roff);
    k_scan_add<<<648, 256, 0, stream>>>(roff, blkoff);
    k_fill<<<2048, 256, 0, stream>>>(srcv, dstv, roff, cur, csr);

    k_proj<<<4096, 256, 0, stream>>>(x, Win, bin, Wres, bres, h0, res);

    float* ha = h0;
    float* hb = h1;
    for (int l = 0; l < N_LAYERS; ++l) {
        k_layer<<<2048, 256, 0, stream>>>(ha, hb, res, roff, csr,
                                          Wroot + (size_t)l * 64 * 64,
                                          Wrel + (size_t)l * 64 * 64,
                                          bconv + l * 64, lng, lnb);
        float* t = ha; ha = hb; hb = t;
    }
    k_out<<<2048, 256, 0, stream>>>(ha, Wout, bout, out);
}